// Round 1
// baseline (354.576 us; speedup 1.0000x reference)
//
#include <hip/hip_runtime.h>
#include <hip/hip_bf16.h>
#include <math.h>

#define NN 100000
#define FF 256
#define EE 128
#define BB 10000
#define DD 32

// ---------------- We = W * z(qz_loga) ----------------
__global__ void k_we(const float* __restrict__ W, const float* __restrict__ qz,
                     float* __restrict__ We) {
  int i = blockIdx.x * 256 + threadIdx.x;
  if (i >= FF * EE) return;
  int f = i >> 7;  // /EE
  float g = qz[f];
  float s = 1.0f / (1.0f + expf(-g));
  float z = s * 1.2f - 0.1f;
  z = fminf(fmaxf(z, 0.0f), 1.0f);
  We[i] = W[i] * z;
}

// ---------------- generic C[M][128] = A(rows)[M][K] @ Bw[K][128] (+bias) ----
// BM=64, BN=128, BK=16, 256 threads, micro-tile 4x8 per thread.
template <int K>
__global__ __launch_bounds__(256) void k_gemm(
    const float* __restrict__ A, const float* __restrict__ Bw,
    const float* __restrict__ bias, const int* __restrict__ idx,
    float* __restrict__ C, int M) {
  __shared__ float As[64][17];   // +1 pad breaks bank aliasing
  __shared__ float Bs[16][128];
  const int tid = threadIdx.x;
  const int tx = tid & 15;        // column group
  const int ty = tid >> 4;        // row group
  const int c0 = tx * 8, r0 = ty * 4;
  const int mb = blockIdx.x * 64;

  // A staging map: each thread loads one float4
  const int lr = tid >> 2;        // 0..63
  const int lk = (tid & 3) * 4;   // 0,4,8,12
  const int arow = mb + lr;
  const bool avalid = arow < M;
  size_t abase = 0;
  if (avalid) {
    int gr = idx ? idx[arow] : arow;
    abase = (size_t)gr * K;
  }
  // B staging map
  const int bk = tid >> 4;        // 0..15
  const int bc = (tid & 15) * 8;

  float acc[4][8];
#pragma unroll
  for (int i = 0; i < 4; ++i)
#pragma unroll
    for (int j = 0; j < 8; ++j) acc[i][j] = 0.0f;

  for (int k0 = 0; k0 < K; k0 += 16) {
    float4 av = make_float4(0.f, 0.f, 0.f, 0.f);
    if (avalid) av = *(const float4*)(A + abase + k0 + lk);
    float4 b0 = *(const float4*)(Bw + (size_t)(k0 + bk) * EE + bc);
    float4 b1 = *(const float4*)(Bw + (size_t)(k0 + bk) * EE + bc + 4);
    As[lr][lk + 0] = av.x; As[lr][lk + 1] = av.y;
    As[lr][lk + 2] = av.z; As[lr][lk + 3] = av.w;
    *(float4*)&Bs[bk][bc] = b0;
    *(float4*)&Bs[bk][bc + 4] = b1;
    __syncthreads();
#pragma unroll
    for (int kk = 0; kk < 16; ++kk) {
      float a0 = As[r0 + 0][kk], a1 = As[r0 + 1][kk];
      float a2 = As[r0 + 2][kk], a3 = As[r0 + 3][kk];
      float4 bb0 = *(float4*)&Bs[kk][c0];
      float4 bb1 = *(float4*)&Bs[kk][c0 + 4];
      float bv[8] = {bb0.x, bb0.y, bb0.z, bb0.w, bb1.x, bb1.y, bb1.z, bb1.w};
#pragma unroll
      for (int j = 0; j < 8; ++j) {
        acc[0][j] = fmaf(a0, bv[j], acc[0][j]);
        acc[1][j] = fmaf(a1, bv[j], acc[1][j]);
        acc[2][j] = fmaf(a2, bv[j], acc[2][j]);
        acc[3][j] = fmaf(a3, bv[j], acc[3][j]);
      }
    }
    __syncthreads();
  }

  float bv[8];
#pragma unroll
  for (int j = 0; j < 8; ++j) bv[j] = bias ? bias[c0 + j] : 0.0f;
#pragma unroll
  for (int i = 0; i < 4; ++i) {
    int row = mb + r0 + i;
    if (row < M) {
      *(float4*)(C + (size_t)row * EE + c0) =
          make_float4(acc[i][0] + bv[0], acc[i][1] + bv[1],
                      acc[i][2] + bv[2], acc[i][3] + bv[3]);
      *(float4*)(C + (size_t)row * EE + c0 + 4) =
          make_float4(acc[i][4] + bv[4], acc[i][5] + bv[5],
                      acc[i][6] + bv[6], acc[i][7] + bv[7]);
    }
  }
}

// ---------------- fused attention: h1 -> h2 -> score -> softmax -> agg ------
__global__ __launch_bounds__(256) void k_attn(
    const float* __restrict__ X, const float* __restrict__ Y,
    const float* __restrict__ P, const int* __restrict__ nodes,
    const int* __restrict__ nidx, const int* __restrict__ nmask,
    const float* __restrict__ w2, const float* __restrict__ b2,
    const float* __restrict__ w3, const float* __restrict__ b3,
    float* __restrict__ out) {
  __shared__ float w2s[64][128];   // half of att2_w, double-staged
  __shared__ float h1s[32][128];
  __shared__ float ps[128];
  __shared__ int nidx_s[32];
  __shared__ float scores_s[32];
  __shared__ float atts[32];
  __shared__ int has_s;
  const int tid = threadIdx.x;
  const int b = blockIdx.x;

  if (tid < 32) nidx_s[tid] = nidx[b * DD + tid];
  if (tid >= 32 && tid < 64) {
    int t = tid - 32;
    ((float4*)ps)[t] = ((const float4*)(P + (size_t)b * EE))[t];
  }
  __syncthreads();

  // stage first half of att2_w
#pragma unroll
  for (int j = 0; j < 8; ++j)
    ((float4*)w2s)[tid + j * 256] = ((const float4*)w2)[tid + j * 256];

  // h1 = relu(Y[neigh] + P[b]) : 8 rows per pass
  {
    const int dg = tid >> 5;          // 0..7
    const int c4 = (tid & 31) * 4;
#pragma unroll
    for (int g = 0; g < 4; ++g) {
      int d = g * 8 + dg;
      int n = nidx_s[d];
      float4 yv = *(const float4*)(Y + (size_t)n * EE + c4);
      float4 pv = *(const float4*)(ps + c4);
      float4 h;
      h.x = fmaxf(yv.x + pv.x, 0.0f);
      h.y = fmaxf(yv.y + pv.y, 0.0f);
      h.z = fmaxf(yv.z + pv.z, 0.0f);
      h.w = fmaxf(yv.w + pv.w, 0.0f);
      *(float4*)&h1s[d][c4] = h;
    }
  }
  __syncthreads();

  const int tx = tid & 31, ty = tid >> 5;
  const int c0 = tx * 4, d0 = ty * 4;
  float acc[4][4];
#pragma unroll
  for (int i = 0; i < 4; ++i)
#pragma unroll
    for (int j = 0; j < 4; ++j) acc[i][j] = 0.0f;

#pragma unroll 8
  for (int k = 0; k < 64; ++k) {
    float4 wv = *(float4*)&w2s[k][c0];
    float a0 = h1s[d0 + 0][k], a1 = h1s[d0 + 1][k];
    float a2 = h1s[d0 + 2][k], a3 = h1s[d0 + 3][k];
    acc[0][0] = fmaf(a0, wv.x, acc[0][0]); acc[0][1] = fmaf(a0, wv.y, acc[0][1]);
    acc[0][2] = fmaf(a0, wv.z, acc[0][2]); acc[0][3] = fmaf(a0, wv.w, acc[0][3]);
    acc[1][0] = fmaf(a1, wv.x, acc[1][0]); acc[1][1] = fmaf(a1, wv.y, acc[1][1]);
    acc[1][2] = fmaf(a1, wv.z, acc[1][2]); acc[1][3] = fmaf(a1, wv.w, acc[1][3]);
    acc[2][0] = fmaf(a2, wv.x, acc[2][0]); acc[2][1] = fmaf(a2, wv.y, acc[2][1]);
    acc[2][2] = fmaf(a2, wv.z, acc[2][2]); acc[2][3] = fmaf(a2, wv.w, acc[2][3]);
    acc[3][0] = fmaf(a3, wv.x, acc[3][0]); acc[3][1] = fmaf(a3, wv.y, acc[3][1]);
    acc[3][2] = fmaf(a3, wv.z, acc[3][2]); acc[3][3] = fmaf(a3, wv.w, acc[3][3]);
  }
  __syncthreads();
  // stage second half of att2_w
#pragma unroll
  for (int j = 0; j < 8; ++j)
    ((float4*)w2s)[tid + j * 256] = ((const float4*)w2)[tid + j * 256 + 2048];
  __syncthreads();
#pragma unroll 8
  for (int k = 64; k < 128; ++k) {
    float4 wv = *(float4*)&w2s[k - 64][c0];
    float a0 = h1s[d0 + 0][k], a1 = h1s[d0 + 1][k];
    float a2 = h1s[d0 + 2][k], a3 = h1s[d0 + 3][k];
    acc[0][0] = fmaf(a0, wv.x, acc[0][0]); acc[0][1] = fmaf(a0, wv.y, acc[0][1]);
    acc[0][2] = fmaf(a0, wv.z, acc[0][2]); acc[0][3] = fmaf(a0, wv.w, acc[0][3]);
    acc[1][0] = fmaf(a1, wv.x, acc[1][0]); acc[1][1] = fmaf(a1, wv.y, acc[1][1]);
    acc[1][2] = fmaf(a1, wv.z, acc[1][2]); acc[1][3] = fmaf(a1, wv.w, acc[1][3]);
    acc[2][0] = fmaf(a2, wv.x, acc[2][0]); acc[2][1] = fmaf(a2, wv.y, acc[2][1]);
    acc[2][2] = fmaf(a2, wv.z, acc[2][2]); acc[2][3] = fmaf(a2, wv.w, acc[2][3]);
    acc[3][0] = fmaf(a3, wv.x, acc[3][0]); acc[3][1] = fmaf(a3, wv.y, acc[3][1]);
    acc[3][2] = fmaf(a3, wv.z, acc[3][2]); acc[3][3] = fmaf(a3, wv.w, acc[3][3]);
  }

  // per-thread partial scores: sum_c relu(h2)*w3
  float4 b2v = *(const float4*)(b2 + c0);
  float4 w3v = *(const float4*)(w3 + c0);
  float sp[4];
#pragma unroll
  for (int i = 0; i < 4; ++i) {
    float h0 = fmaxf(acc[i][0] + b2v.x, 0.0f);
    float h1 = fmaxf(acc[i][1] + b2v.y, 0.0f);
    float h2 = fmaxf(acc[i][2] + b2v.z, 0.0f);
    float h3 = fmaxf(acc[i][3] + b2v.w, 0.0f);
    sp[i] = h0 * w3v.x + h1 * w3v.y + h2 * w3v.z + h3 * w3v.w;
  }
#pragma unroll
  for (int m = 1; m <= 16; m <<= 1) {
#pragma unroll
    for (int i = 0; i < 4; ++i) sp[i] += __shfl_xor(sp[i], m);
  }
  if (tx == 0) {
#pragma unroll
    for (int i = 0; i < 4; ++i) scores_s[d0 + i] = sp[i];
  }
  __syncthreads();

  // softmax over D=32 (first 32 threads)
  if (tid < 32) {
    int m = nmask[b * DD + tid];
    float s = scores_s[tid] + b3[0];
    if (!m) s = -1e30f;
    float mx = s;
#pragma unroll
    for (int o = 1; o <= 16; o <<= 1) mx = fmaxf(mx, __shfl_xor(mx, o));
    float e = expf(s - mx);
    float sm = e;
#pragma unroll
    for (int o = 1; o <= 16; o <<= 1) sm += __shfl_xor(sm, o);
    atts[tid] = e / sm;
    unsigned long long bal = __ballot(m != 0);
    if (tid == 0) has_s = (bal != 0ull) ? 1 : 0;
  }
  __syncthreads();

  // agg = sum_d att[d] * X[neigh[d]]  (or node_feat fallback)
  if (tid < EE) {
    float a;
    if (has_s) {
      a = 0.0f;
#pragma unroll 4
      for (int d = 0; d < 32; ++d)
        a += atts[d] * X[(size_t)nidx_s[d] * EE + tid];
    } else {
      a = X[(size_t)nodes[b] * EE + tid];
    }
    out[(size_t)b * EE + tid] = a;
  }
}

extern "C" void kernel_launch(void* const* d_in, const int* in_sizes, int n_in,
                              void* d_out, int out_size, void* d_ws,
                              size_t ws_size, hipStream_t stream) {
  const int* nodes = (const int*)d_in[0];
  const int* nidx = (const int*)d_in[1];
  const int* nmask = (const int*)d_in[2];
  const float* feature = (const float*)d_in[3];
  const float* W = (const float*)d_in[4];
  const float* bb = (const float*)d_in[5];
  const float* qz = (const float*)d_in[6];
  const float* a1w = (const float*)d_in[7];
  const float* a1b = (const float*)d_in[8];
  const float* a2w = (const float*)d_in[9];
  const float* a2b = (const float*)d_in[10];
  const float* a3w = (const float*)d_in[11];
  const float* a3b = (const float*)d_in[12];
  float* out = (float*)d_out;

  char* ws = (char*)d_ws;
  float* We = (float*)ws;                                  // 128 KiB
  float* X = (float*)(ws + (size_t)131072);                // 51.2 MB
  float* Yv = (float*)(ws + (size_t)131072 + 51200000);    // 51.2 MB
  float* Pv = (float*)(ws + (size_t)131072 + 102400000);   // 5.12 MB

  k_we<<<128, 256, 0, stream>>>(W, qz, We);
  // X = feature @ We + b            [100000,256]@[256,128]
  k_gemm<256><<<(NN + 63) / 64, 256, 0, stream>>>(feature, We, bb, nullptr, X, NN);
  // Y = X @ att1_w[:128] + att1_b   [100000,128]@[128,128]
  k_gemm<128><<<(NN + 63) / 64, 256, 0, stream>>>(X, a1w, a1b, nullptr, Yv, NN);
  // P = X[nodes] @ att1_w[128:]     [10000,128]@[128,128]
  k_gemm<128><<<(BB + 63) / 64, 256, 0, stream>>>(X, a1w + 128 * 128, nullptr,
                                                  nodes, Pv, BB);
  // fused attention + aggregation
  k_attn<<<BB, 256, 0, stream>>>(X, Yv, Pv, nodes, nidx, nmask, a2w, a2b, a3w,
                                 a3b, out);
}

// Round 2
// 123.800 us; speedup vs baseline: 2.8641x; 2.8641x over previous
//
#include <hip/hip_runtime.h>
#include <hip/hip_bf16.h>
#include <math.h>

#define NN 100000
#define FF 256
#define EE 128
#define BB_ 10000
#define DD 32

typedef __attribute__((ext_vector_type(8))) short short8;
typedef __attribute__((ext_vector_type(4))) float f32x4;

__device__ __forceinline__ short f2bf(float f) {
  union { float f; unsigned u; } v; v.f = f;
  unsigned r = v.u + 0x7fffu + ((v.u >> 16) & 1u);
  return (short)(r >> 16);
}
__device__ __forceinline__ float bf2f(short s) {
  union { unsigned u; float f; } v;
  v.u = ((unsigned)(unsigned short)s) << 16;
  return v.f;
}

// ---- prep: We=W*z and bf16 [N][K] transposes of all weights ----
__global__ __launch_bounds__(256) void k_prep(
    const float* __restrict__ W, const float* __restrict__ qz,
    const float* __restrict__ a1w, const float* __restrict__ a2w,
    short* __restrict__ WeT, short* __restrict__ a1wTn,
    short* __restrict__ a1wTc, short* __restrict__ w2T) {
  int i = blockIdx.x * 256 + threadIdx.x;
  if (i < 32768) {                       // WeT[e][f] = W[f][e]*z(f)
    int e = i >> 8, f = i & 255;
    float g = qz[f];
    float s = 1.0f / (1.0f + expf(-g));
    float z = fminf(fmaxf(s * 1.2f - 0.1f, 0.0f), 1.0f);
    WeT[e * 256 + f] = f2bf(W[f * 128 + e] * z);
  } else if (i < 49152) {                // a1wTn[n][k] = a1w[k][n]
    int t = i - 32768; int n = t >> 7, k = t & 127;
    a1wTn[n * 128 + k] = f2bf(a1w[k * 128 + n]);
  } else if (i < 65536) {                // a1wTc[n][k] = a1w[128+k][n]
    int t = i - 49152; int n = t >> 7, k = t & 127;
    a1wTc[n * 128 + k] = f2bf(a1w[(128 + k) * 128 + n]);
  } else if (i < 81920) {                // w2T[n][k] = a2w[k][n]
    int t = i - 65536; int n = t >> 7, k = t & 127;
    w2T[n * 128 + k] = f2bf(a2w[k * 128 + n]);
  }
}

// ---- MFMA GEMM: C[M][128] = A(rows via idx)[M][K] @ BT[128][K]^T + bias ----
// tile 128x128, BK=64, 4 waves, 16x16x32 bf16 MFMA, XOR-swizzled LDS.
template <int K, bool AF32, bool OUTBF16>
__global__ __launch_bounds__(256) void k_mm(
    const void* __restrict__ Ap, const short* __restrict__ BT,
    const float* __restrict__ bias, const int* __restrict__ idx,
    void* __restrict__ Cp, int M) {
  __shared__ short As[128 * 64];
  __shared__ short Bs[128 * 64];
  const int tid = threadIdx.x;
  const int mb = blockIdx.x * 128;
  const int wave = tid >> 6, lane = tid & 63;
  const int wr = wave >> 1, wc = wave & 1;
  const int l15 = lane & 15, lg = lane >> 4;

  size_t abase[4];
#pragma unroll
  for (int s = 0; s < 4; ++s) {
    int row = (tid + s * 256) >> 3;
    int grow = mb + row;
    int gr = 0;
    if (grow < M) gr = idx ? idx[grow] : grow;
    abase[s] = (size_t)gr * K;
  }

  f32x4 acc[4][4];
#pragma unroll
  for (int i = 0; i < 4; ++i)
#pragma unroll
    for (int j = 0; j < 4; ++j) acc[i][j] = (f32x4){0.f, 0.f, 0.f, 0.f};

  for (int k0 = 0; k0 < K; k0 += 64) {
#pragma unroll
    for (int s = 0; s < 4; ++s) {
      int q = tid + s * 256;
      int row = q >> 3, c = q & 7;
      short8 av;
      if (AF32) {
        const float* ap = (const float*)Ap + abase[s] + k0 + c * 8;
        float4 f0 = *(const float4*)ap;
        float4 f1 = *(const float4*)(ap + 4);
        av[0] = f2bf(f0.x); av[1] = f2bf(f0.y);
        av[2] = f2bf(f0.z); av[3] = f2bf(f0.w);
        av[4] = f2bf(f1.x); av[5] = f2bf(f1.y);
        av[6] = f2bf(f1.z); av[7] = f2bf(f1.w);
      } else {
        av = *(const short8*)((const short*)Ap + abase[s] + k0 + c * 8);
      }
      *(short8*)(As + row * 64 + 8 * (c ^ (row & 7))) = av;
      short8 bv = *(const short8*)(BT + (size_t)row * K + k0 + c * 8);
      *(short8*)(Bs + row * 64 + 8 * (c ^ (row & 7))) = bv;
    }
    __syncthreads();
#pragma unroll
    for (int ks = 0; ks < 2; ++ks) {
      int c = ks * 4 + lg;
      short8 af[4], bfv[4];
#pragma unroll
      for (int i = 0; i < 4; ++i) {
        int r = wr * 64 + i * 16 + l15;
        af[i] = *(short8*)(As + r * 64 + 8 * (c ^ (r & 7)));
        int n = wc * 64 + i * 16 + l15;
        bfv[i] = *(short8*)(Bs + n * 64 + 8 * (c ^ (n & 7)));
      }
#pragma unroll
      for (int i = 0; i < 4; ++i)
#pragma unroll
        for (int j = 0; j < 4; ++j)
          acc[i][j] = __builtin_amdgcn_mfma_f32_16x16x32_bf16(
              af[i], bfv[j], acc[i][j], 0, 0, 0);
    }
    __syncthreads();
  }

  float bv4[4];
#pragma unroll
  for (int j = 0; j < 4; ++j) {
    int col = wc * 64 + j * 16 + l15;
    bv4[j] = bias ? bias[col] : 0.f;
  }
#pragma unroll
  for (int i = 0; i < 4; ++i) {
#pragma unroll
    for (int r = 0; r < 4; ++r) {
      int row = mb + wr * 64 + i * 16 + lg * 4 + r;
      if (row < M) {
#pragma unroll
        for (int j = 0; j < 4; ++j) {
          int col = wc * 64 + j * 16 + l15;
          float v = acc[i][j][r] + bv4[j];
          if (OUTBF16)
            ((short*)Cp)[(size_t)row * EE + col] = f2bf(v);
          else
            ((float*)Cp)[(size_t)row * EE + col] = v;
        }
      }
    }
  }
}

// ---- fused attention: 4 centers/block, MFMA att2, softmax, agg ----
__global__ __launch_bounds__(256) void k_attn2(
    const short* __restrict__ X, const short* __restrict__ Y,
    const float* __restrict__ P, const int* __restrict__ nodes,
    const int* __restrict__ nidx, const int* __restrict__ nmask,
    const short* __restrict__ w2T, const float* __restrict__ b2,
    const float* __restrict__ w3, const float* __restrict__ b3,
    float* __restrict__ out) {
  __shared__ short h1s[128 * 128];
  __shared__ int nidx_s[128];
  __shared__ float scores_s[256];
  __shared__ float atts_s[128];
  __shared__ int has_sh[4];
  const int tid = threadIdx.x;
  const int b0 = blockIdx.x * 4;
  const int wave = tid >> 6, lane = tid & 63;
  const int wr = wave >> 1, wc = wave & 1;
  const int l15 = lane & 15, lg = lane >> 4;

  if (tid < 128) nidx_s[tid] = nidx[b0 * DD + tid];
  __syncthreads();

  // h1 = relu(Y[neigh] + P[center]) -> bf16, swizzled LDS [row][k]
#pragma unroll
  for (int s = 0; s < 8; ++s) {
    int q = tid + s * 256;
    int row = q >> 4, c = q & 15;
    int n = nidx_s[row];
    short8 yv = *(const short8*)(Y + (size_t)n * EE + c * 8);
    const float* pp = P + (size_t)(b0 + (row >> 5)) * EE + c * 8;
    float4 p0 = *(const float4*)pp;
    float4 p1 = *(const float4*)(pp + 4);
    float pf[8] = {p0.x, p0.y, p0.z, p0.w, p1.x, p1.y, p1.z, p1.w};
    short8 hv;
#pragma unroll
    for (int j = 0; j < 8; ++j)
      hv[j] = f2bf(fmaxf(bf2f(yv[j]) + pf[j], 0.f));
    *(short8*)(h1s + row * 128 + 8 * ((c & 8) | ((c ^ row) & 7))) = hv;
  }
  __syncthreads();

  // C[128][128] = h1 @ w2 ; B fragments straight from global w2T (L1/L2)
  f32x4 acc[4][4];
#pragma unroll
  for (int i = 0; i < 4; ++i)
#pragma unroll
    for (int j = 0; j < 4; ++j) acc[i][j] = (f32x4){0.f, 0.f, 0.f, 0.f};

#pragma unroll
  for (int ks = 0; ks < 4; ++ks) {
    int c = ks * 4 + lg;
    short8 af[4], bfv[4];
#pragma unroll
    for (int i = 0; i < 4; ++i) {
      int r = wr * 64 + i * 16 + l15;
      af[i] = *(short8*)(h1s + r * 128 + 8 * ((c & 8) | ((c ^ r) & 7)));
      int n = wc * 64 + i * 16 + l15;
      bfv[i] = *(const short8*)(w2T + n * 128 + c * 8);
    }
#pragma unroll
    for (int i = 0; i < 4; ++i)
#pragma unroll
      for (int j = 0; j < 4; ++j)
        acc[i][j] = __builtin_amdgcn_mfma_f32_16x16x32_bf16(
            af[i], bfv[j], acc[i][j], 0, 0, 0);
  }

  // scores: per-row sum over cols of relu(h2)*w3, reduce across l15 group
  float b2v[4], w3v[4];
#pragma unroll
  for (int j = 0; j < 4; ++j) {
    int col = wc * 64 + j * 16 + l15;
    b2v[j] = b2[col];
    w3v[j] = w3[col];
  }
  float part[16];
#pragma unroll
  for (int i = 0; i < 4; ++i)
#pragma unroll
    for (int r = 0; r < 4; ++r) {
      float s = 0.f;
#pragma unroll
      for (int j = 0; j < 4; ++j)
        s += fmaxf(acc[i][j][r] + b2v[j], 0.f) * w3v[j];
      part[i * 4 + r] = s;
    }
#pragma unroll
  for (int off = 1; off <= 8; off <<= 1) {
#pragma unroll
    for (int t = 0; t < 16; ++t) part[t] += __shfl_xor(part[t], off);
  }
  if (l15 == 0) {
#pragma unroll
    for (int i = 0; i < 4; ++i)
#pragma unroll
      for (int r = 0; r < 4; ++r) {
        int row = wr * 64 + i * 16 + lg * 4 + r;
        scores_s[row * 2 + wc] = part[i * 4 + r];
      }
  }
  __syncthreads();

  // softmax: wave g handles center g (32 rows, lanes 0..31)
  float b3v = b3[0];
  if (lane < 32) {
    int row = wave * 32 + lane;
    int m = nmask[(size_t)(b0 + wave) * DD + lane];
    float s = scores_s[row * 2] + scores_s[row * 2 + 1] + b3v;
    if (!m) s = -1e30f;
    float mx = s;
#pragma unroll
    for (int off = 1; off <= 16; off <<= 1) mx = fmaxf(mx, __shfl_xor(mx, off));
    float e = expf(s - mx);
    float sum = e;
#pragma unroll
    for (int off = 1; off <= 16; off <<= 1) sum += __shfl_xor(sum, off);
    atts_s[row] = e / sum;
    unsigned long long bal = __ballot(m != 0);
    if (lane == 0) has_sh[wave] = (bal != 0ull) ? 1 : 0;
  }
  __syncthreads();

  // agg: wave g aggregates center g; each lane owns cols lane and lane+64
  {
    int g = wave;
    float a0 = 0.f, a1 = 0.f;
    if (has_sh[g]) {
#pragma unroll 4
      for (int d = 0; d < 32; ++d) {
        float a = atts_s[g * 32 + d];
        const short* xr = X + (size_t)nidx_s[g * 32 + d] * EE;
        a0 += a * bf2f(xr[lane]);
        a1 += a * bf2f(xr[lane + 64]);
      }
    } else {
      const short* xr = X + (size_t)nodes[b0 + g] * EE;
      a0 = bf2f(xr[lane]);
      a1 = bf2f(xr[lane + 64]);
    }
    out[(size_t)(b0 + g) * EE + lane] = a0;
    out[(size_t)(b0 + g) * EE + lane + 64] = a1;
  }
}

extern "C" void kernel_launch(void* const* d_in, const int* in_sizes, int n_in,
                              void* d_out, int out_size, void* d_ws,
                              size_t ws_size, hipStream_t stream) {
  const int* nodes = (const int*)d_in[0];
  const int* nidx = (const int*)d_in[1];
  const int* nmask = (const int*)d_in[2];
  const float* feature = (const float*)d_in[3];
  const float* W = (const float*)d_in[4];
  const float* bb = (const float*)d_in[5];
  const float* qz = (const float*)d_in[6];
  const float* a1w = (const float*)d_in[7];
  const float* a1b = (const float*)d_in[8];
  const float* a2w = (const float*)d_in[9];
  const float* a2b = (const float*)d_in[10];
  const float* a3w = (const float*)d_in[11];
  const float* a3b = (const float*)d_in[12];
  float* out = (float*)d_out;

  char* ws = (char*)d_ws;
  short* WeT   = (short*)(ws);                       // 64 KiB
  short* a1wTn = (short*)(ws + 65536);               // 32 KiB
  short* a1wTc = (short*)(ws + 98304);               // 32 KiB
  short* w2T   = (short*)(ws + 131072);              // 32 KiB
  short* Xb    = (short*)(ws + 163840);              // 25.6 MB bf16
  short* Yb    = (short*)(ws + 163840 + 25600000);   // 25.6 MB bf16
  float* Pv    = (float*)(ws + 163840 + 51200000);   // 5.12 MB fp32

  k_prep<<<320, 256, 0, stream>>>(W, qz, a1w, a2w, WeT, a1wTn, a1wTc, w2T);
  // X = feature @ We + b        [100000,256]x[256,128] -> bf16
  k_mm<256, true, true><<<(NN + 127) / 128, 256, 0, stream>>>(
      feature, WeT, bb, nullptr, Xb, NN);
  // Y = X @ att1_w[:128] + a1b  [100000,128]x[128,128] -> bf16
  k_mm<128, false, true><<<(NN + 127) / 128, 256, 0, stream>>>(
      Xb, a1wTn, a1b, nullptr, Yb, NN);
  // P = X[nodes] @ att1_w[128:] [10000,128]x[128,128] -> fp32
  k_mm<128, false, false><<<(BB_ + 127) / 128, 256, 0, stream>>>(
      Xb, a1wTc, nullptr, nodes, Pv, BB_);
  // fused attention + aggregation (4 centers per block)
  k_attn2<<<BB_ / 4, 256, 0, stream>>>(Xb, Yb, Pv, nodes, nidx, nmask, w2T,
                                       a2b, a3w, a3b, out);
}